// Round 9
// baseline (81.547 us; speedup 1.0000x reference)
//
#include <hip/hip_runtime.h>
#include <hip/hip_bf16.h>

// Two-kernel separable tile-gather.
// out[b,c,h,w] = (1/64) Σ_n Σ_p ey(h,p) Σ_q ex(w,q) * patchP[b,n,c,p,q]
// where patchP = patch * invZx[q] * invZy[p] is pre-folded by brush_prep
// (exact vs reference up to fp reassociation), so the main kernel evaluates
// only unnormalized Gaussians ex,ey (incremental: 2 exps per axis).
// sigma=0.2 -> support radius 2 px => brush window <=20x20 px.
//
// brush_prep: one block per (b,n); per-wave redundant invZ (no barrier);
//             writes patchP (6 MB) into d_ws.
// brush_tile: one block per 16x16 tile; wave-private ballot (~1.2 survivors);
//             per brush ONE barrier:
//               stage1: T4[wi][p] = Σ_j ex_j * patchP[:,p,qlo+j] via
//                       intra-wave __shfl (branchless — ds_bpermute from
//                       exec-masked lanes is undefined, weights mask instead)
//               barrier; stage2: 5 p-taps per pixel from T4.
//             T4 double-buffered: iter k reads buf k&1; iter k+2 writes the
//             same buf only after barrier k+1, which iter-k readers must have
//             reached (reads precede their own arrival) => WAR safe.
//             Patch loads for brush k+1 issue before stage1 of brush k
//             (mask known upfront) => L2 latency hidden.
// Incremental Gaussian: w_{j+1}=w_j*u, u*=exp(-25); d0 clamped to [-3,3]
// keeps the chain finite for weight-masked lanes (0*finite==0).

#define E25 1.3887944e-11f   // exp(-25)

__global__ __launch_bounds__(256) void brush_prep(
        const float* __restrict__ brushes,   // [32,64,2]
        const float* __restrict__ patches,   // [32,64,3,16,16]
        float* __restrict__ patchP)          // [32,64,3,16,16] in d_ws
{
    const int bn   = blockIdx.x;             // b*64 + n
    const int tid  = threadIdx.x;
    const int lane = tid & 63;
    const int qi   = tid & 15;
    const int pi   = tid >> 4;

    const float2 g = ((const float2*)brushes)[bn];
    const float gx = g.x * 256.0f, gy = g.y * 256.0f;

    // per-wave redundant normalizer: lane k&31 -> axis k>>4, tap k&15
    const int k = lane & 31;
    const float gg = (k >> 4) ? gy : gx;
    const float mu = gg + (float)(k & 15) - 7.5f;
    const float fl = floorf(mu);
    float Z = 0.0f;
#pragma unroll
    for (int d = -1; d <= 2; ++d) {
        const float c = fl + (float)d;
        if (c >= -8.0f && c <= 263.0f) {     // padded coord range
            const float u = c - mu;
            Z += __expf(-12.5f * u * u);
        }
    }
    const float invz = 1.0f / (Z + 1e-7f);
    const float s = __shfl(invz, qi, 64) * __shfl(invz, 16 + pi, 64);

    const float* pb = patches + (size_t)bn * 768;
    float*       wp = patchP  + (size_t)bn * 768;
    wp[tid]       = pb[tid]       * s;
    wp[tid + 256] = pb[tid + 256] * s;
    wp[tid + 512] = pb[tid + 512] * s;
}

__global__ __launch_bounds__(256) void brush_tile(
        const float* __restrict__ brushes,   // [32,64,2]
        const float* __restrict__ patchP,    // [32,64,3,16,16] pre-folded
        float* __restrict__ out)             // [32,3,256,256]
{
    const int b    = blockIdx.z;
    const int tx   = blockIdx.x << 4;
    const int ty   = blockIdx.y << 4;
    const int tid  = threadIdx.x;
    const int lane = tid & 63;
    const int qi   = tid & 15;   // q (source) / wi (stage1) / w-col (stage2)
    const int pi   = tid >> 4;   // p (source) / h-row (stage2)
    const int w    = tx + qi;
    const int h    = ty + pi;

    // [buf][wi][p(16)+pad5] float4, c-packed; stride 21
    __shared__ float4 T4[2 * 16 * 21];

    // zero p>=16 pads of both buffers once (stage1 writes only p<16);
    // the first brush's barrier orders these vs the first stage2 reads
    if (tid < 160) {
        const int buf = tid / 80, r = tid % 80;
        T4[buf * 336 + (r / 5) * 21 + 16 + (r % 5)] = make_float4(0, 0, 0, 0);
    }

    // wave-private brush table + ballot (identical masks in all waves)
    const float2 g0 = ((const float2*)brushes)[(b << 6) + lane];
    const float bx = g0.x * 256.0f, by = g0.y * 256.0f;
    const bool hit =
        (bx >= (float)tx - 9.5f) & (bx <= (float)tx + 24.5f) &
        (by >= (float)ty - 9.5f) & (by <= (float)ty + 24.5f);
    unsigned long long mask = __ballot(hit);

    float acc0 = 0.0f, acc1 = 0.0f, acc2 = 0.0f;

    if (mask) {                              // block-uniform
        int n = __builtin_ctzll(mask);
        mask &= mask - 1;
        const float* wp = patchP + (size_t)((b << 6) + n) * 768;
        float a0 = wp[tid], a1 = wp[tid + 256], a2 = wp[tid + 512];
        int it = 0;

        while (true) {                       // uniform trip count
            // prefetch next brush's patch before this brush's compute
            int nn = -1;
            float p0, p1, p2;
            if (mask) {
                nn = __builtin_ctzll(mask);
                mask &= mask - 1;
                const float* wq = patchP + (size_t)((b << 6) + nn) * 768;
                p0 = wq[tid]; p1 = wq[tid + 256]; p2 = wq[tid + 512];
            }

            const float gx = __shfl(bx, n, 64);   // uniform n -> readlane
            const float gy = __shfl(by, n, 64);
            const int buf = (it & 1) * 336;

            // ---- stage1: T4[wi=qi][p=pi], branchless shuffles ----------
            {
                const float ax  = (float)w - gx + 7.5f;
                const bool  okx = (ax >= -2.5f) & (ax <= 17.5f);
                int qlo = (int)ceilf(ax - 2.0f);
                qlo = qlo < 0 ? 0 : (qlo > 15 ? 15 : qlo);
                float d0 = ax - (float)qlo;
                d0 = fminf(fmaxf(d0, -3.0f), 3.0f);   // keep exp chain finite
                float wgt = okx ? __expf(-12.5f * d0 * d0) : 0.0f;
                float u   = __expf(25.0f * d0 - 12.5f);
                const int base = ((pi & 3) << 4) + qlo;  // intra-wave src
                float4 s = make_float4(0, 0, 0, 0);
#pragma unroll
                for (int j = 0; j < 5; ++j) {
                    const float t0 = __shfl(a0, base + j, 64);  // all active
                    const float t1 = __shfl(a1, base + j, 64);
                    const float t2 = __shfl(a2, base + j, 64);
                    const float wj = (qlo + j < 16) ? wgt : 0.0f;
                    s.x += wj * t0; s.y += wj * t1; s.z += wj * t2;
                    wgt *= u; u *= E25;
                }
                T4[buf + qi * 21 + pi] = s;
            }
            __syncthreads();                 // the one barrier per brush

            // ---- stage2: 5 p-taps from T4 (pads exact zeros) -----------
            {
                const float ay = (float)h - gy + 7.5f;
                if (ay >= -2.5f && ay <= 17.5f) {   // divergent ok: LDS only
                    int plo = (int)ceilf(ay - 2.0f);
                    plo = plo < 0 ? 0 : (plo > 15 ? 15 : plo);
                    const float d0 = ay - (float)plo;    // in [-2.5, 2.5]
                    float wgt = __expf(-12.5f * d0 * d0);
                    float u   = __expf(25.0f * d0 - 12.5f);
                    const float4* row = &T4[buf + qi * 21 + plo];
#pragma unroll
                    for (int j = 0; j < 5; ++j) {
                        const float4 v = row[j];
                        acc0 += wgt * v.x; acc1 += wgt * v.y; acc2 += wgt * v.z;
                        wgt *= u; u *= E25;
                    }
                }
            }

            if (nn < 0) break;
            n = nn; a0 = p0; a1 = p1; a2 = p2; ++it;
        }
    }

    const float sc = 1.0f / 64.0f;
    float* ob = out + (((size_t)(b * 3)) << 16) + (h << 8) + w;
    ob[0]       = acc0 * sc;
    ob[1 << 16] = acc1 * sc;
    ob[2 << 16] = acc2 * sc;
}

extern "C" void kernel_launch(void* const* d_in, const int* in_sizes, int n_in,
                              void* d_out, int out_size, void* d_ws, size_t ws_size,
                              hipStream_t stream) {
    const float* brushes = (const float*)d_in[0];
    const float* patches = (const float*)d_in[1];
    float* out    = (float*)d_out;
    float* patchP = (float*)d_ws;            // 32*64*768 floats = 6 MB
    brush_prep<<<dim3(32 * 64), dim3(256), 0, stream>>>(brushes, patches, patchP);
    brush_tile<<<dim3(16, 16, 32), dim3(256), 0, stream>>>(brushes, patchP, out);
}